// Round 1
// baseline (752.297 us; speedup 1.0000x reference)
//
#include <hip/hip_runtime.h>

#define NNODES 100000
#define NEDGES 1600000

// ---------------- edge dtype detect: int64 vs int32 ----------------
// If edge_index is int64 little-endian, odd 32-bit words (hi halves) are all 0.
__global__ void detect_kernel(const int* __restrict__ ei, int* __restrict__ flag) {
    int t = threadIdx.x;                 // 0..63
    int v = ei[2 * t + 1];
    unsigned long long nz = __ballot(v != 0);
    if (t == 0) flag[0] = (nz == 0ULL) ? 1 : 0;   // 1 => int64 layout
}

__device__ __forceinline__ int load_src(const int* ei, int is64, int e) {
    return is64 ? ei[2 * e] : ei[e];
}
__device__ __forceinline__ int load_dst(const int* ei, int is64, int e) {
    return is64 ? ei[2 * (NEDGES + e)] : ei[NEDGES + e];
}

// ---------------- CSR build ----------------
__global__ void hist_kernel(const int* __restrict__ ei, const int* __restrict__ flag,
                            int* __restrict__ deg) {
    int is64 = flag[0];
    for (int e = blockIdx.x * blockDim.x + threadIdx.x; e < NEDGES;
         e += gridDim.x * blockDim.x) {
        atomicAdd(&deg[load_dst(ei, is64, e)], 1);
    }
}

// pass 1: per-block (1024 elems) sums
__global__ void scan_bsum(const int* __restrict__ deg, int* __restrict__ bsums) {
    int b = blockIdx.x, t = threadIdx.x;
    long i0 = (long)b * 1024 + (long)t * 4;
    int v0 = 0, v1 = 0, v2 = 0, v3 = 0;
    if (i0 + 3 < NNODES) {
        int4 q = *(const int4*)&deg[i0];
        v0 = q.x; v1 = q.y; v2 = q.z; v3 = q.w;
    } else {
        if (i0 + 0 < NNODES) v0 = deg[i0 + 0];
        if (i0 + 1 < NNODES) v1 = deg[i0 + 1];
        if (i0 + 2 < NNODES) v2 = deg[i0 + 2];
        if (i0 + 3 < NNODES) v3 = deg[i0 + 3];
    }
    int s = v0 + v1 + v2 + v3;
    for (int off = 32; off > 0; off >>= 1) s += __shfl_down(s, off);
    __shared__ int ws[4];
    if ((t & 63) == 0) ws[t >> 6] = s;
    __syncthreads();
    if (t == 0) bsums[b] = ws[0] + ws[1] + ws[2] + ws[3];
}

// pass 2: exclusive scan of the (<=128) block sums
__global__ void scan_partials(int* __restrict__ bsums, int nb) {
    __shared__ int sm[128];
    int t = threadIdx.x;
    int v = (t < nb) ? bsums[t] : 0;
    int run = v;
    sm[t] = run;
    __syncthreads();
    for (int off = 1; off < 128; off <<= 1) {
        int other = (t >= off) ? sm[t - off] : 0;
        __syncthreads();
        run += other;
        sm[t] = run;
        __syncthreads();
    }
    if (t < nb) bsums[t] = run - v;      // exclusive
}

// pass 3: write exclusive offsets
__global__ void scan_write(const int* __restrict__ deg, const int* __restrict__ bsums,
                           int* __restrict__ offs) {
    int b = blockIdx.x, t = threadIdx.x;
    long i0 = (long)b * 1024 + (long)t * 4;
    int v0 = 0, v1 = 0, v2 = 0, v3 = 0;
    if (i0 + 3 < NNODES) {
        int4 q = *(const int4*)&deg[i0];
        v0 = q.x; v1 = q.y; v2 = q.z; v3 = q.w;
    } else {
        if (i0 + 0 < NNODES) v0 = deg[i0 + 0];
        if (i0 + 1 < NNODES) v1 = deg[i0 + 1];
        if (i0 + 2 < NNODES) v2 = deg[i0 + 2];
        if (i0 + 3 < NNODES) v3 = deg[i0 + 3];
    }
    int tot = v0 + v1 + v2 + v3;
    __shared__ int sm[256];
    int run = tot;
    sm[t] = run;
    __syncthreads();
    for (int off = 1; off < 256; off <<= 1) {
        int other = (t >= off) ? sm[t - off] : 0;
        __syncthreads();
        run += other;
        sm[t] = run;
        __syncthreads();
    }
    int excl = run - tot + bsums[b];
    if (i0 + 0 < NNODES) offs[i0 + 0] = excl;
    if (i0 + 1 < NNODES) offs[i0 + 1] = excl + v0;
    if (i0 + 2 < NNODES) offs[i0 + 2] = excl + v0 + v1;
    if (i0 + 3 < NNODES) offs[i0 + 3] = excl + v0 + v1 + v2;
    if (b == 0 && t == 0) offs[NNODES] = NEDGES;
}

__global__ void copy_kernel(const int* __restrict__ src, int* __restrict__ dst) {
    int i = blockIdx.x * blockDim.x + threadIdx.x;
    if (i < NNODES) dst[i] = src[i];
}

__global__ void scatter_kernel(const int* __restrict__ ei, const int* __restrict__ flag,
                               int* __restrict__ cursor, int* __restrict__ csr) {
    int is64 = flag[0];
    for (int e = blockIdx.x * blockDim.x + threadIdx.x; e < NEDGES;
         e += gridDim.x * blockDim.x) {
        int s = load_src(ei, is64, e);
        int d = load_dst(ei, is64, e);
        int pos = atomicAdd(&cursor[d], 1);
        csr[pos] = s;
    }
}

// ---------------- fused dual GEMM: zl = h@wl ; zr = h@wr + b ----------------
template <int K, int NOUT>
__global__ __launch_bounds__(256) void gemm_fused(
    const float* __restrict__ h, const float* __restrict__ wl,
    const float* __restrict__ wr, const float* __restrict__ bias,
    float* __restrict__ zl, float* __restrict__ zr, int nrows) {
    __shared__ float wl_s[K * 64];
    __shared__ float wr_s[K * 64];
    __shared__ float h_s[8][K];
    int t = threadIdx.x;
    for (int idx = t; idx < K * 64; idx += 256) {
        int k = idx >> 6, j = idx & 63;
        wl_s[idx] = (j < NOUT) ? wl[k * NOUT + j] : 0.f;
        wr_s[idx] = (j < NOUT) ? wr[k * NOUT + j] : 0.f;
    }
    int j2  = (t & 31) * 2;
    int sub = t >> 5;             // 0..7
    float b0 = 0.f, b1v = 0.f;
    if (j2 + 1 < NOUT || j2 < NOUT) { }   // keep simple guards below
    if (j2 < NOUT) { b0 = bias[j2]; b1v = bias[j2 + 1]; }

    for (int rb = blockIdx.x * 8; rb < nrows; rb += gridDim.x * 8) {
        __syncthreads();          // protects w_s (first iter) and h_s reuse
        if (K == 128) {
            int row = t >> 5, kk = (t & 31) * 4;
            float4 hv = make_float4(0.f, 0.f, 0.f, 0.f);
            if (rb + row < nrows) hv = *(const float4*)&h[(long)(rb + row) * K + kk];
            *(float4*)&h_s[row][kk] = hv;
        } else {                  // K == 64
            if (t < 128) {
                int row = t >> 4, kk = (t & 15) * 4;
                float4 hv = make_float4(0.f, 0.f, 0.f, 0.f);
                if (rb + row < nrows) hv = *(const float4*)&h[(long)(rb + row) * K + kk];
                *(float4*)&h_s[row][kk] = hv;
            }
        }
        __syncthreads();
        float al0 = 0.f, al1 = 0.f, ar0 = 0.f, ar1 = 0.f;
        for (int k = 0; k < K; k += 4) {
            float4 hv = *(const float4*)&h_s[sub][k];
            float hh[4] = {hv.x, hv.y, hv.z, hv.w};
#pragma unroll
            for (int kk = 0; kk < 4; ++kk) {
                float2 a = *(const float2*)&wl_s[(k + kk) * 64 + j2];
                float2 c = *(const float2*)&wr_s[(k + kk) * 64 + j2];
                al0 += hh[kk] * a.x; al1 += hh[kk] * a.y;
                ar0 += hh[kk] * c.x; ar1 += hh[kk] * c.y;
            }
        }
        int i = rb + sub;
        if (i < nrows && j2 < NOUT) {
            zl[(long)i * NOUT + j2]     = al0;
            zl[(long)i * NOUT + j2 + 1] = al1;
            zr[(long)i * NOUT + j2]     = ar0 + b0;
            zr[(long)i * NOUT + j2 + 1] = ar1 + b1v;
        }
    }
}

// ---------------- aggregate + combine + epilogue ----------------
// MODE: 0 = relu, 1 = bn+relu, 2 = bn
template <int NOUT, int MODE>
__global__ __launch_bounds__(256) void combine_kernel(
    const float* __restrict__ zl, const float* __restrict__ zr,
    const int* __restrict__ offs, const int* __restrict__ csr,
    const float* __restrict__ g, const float* __restrict__ bb,
    const float* __restrict__ m, const float* __restrict__ v,
    float* __restrict__ out) {
    int wid  = (blockIdx.x * blockDim.x + threadIdx.x) >> 6;
    int lane = threadIdx.x & 63;
    if (wid >= NNODES) return;
    int s0 = offs[wid], s1 = offs[wid + 1];
    float acc = 0.f;
    for (int base = s0; base < s1; base += 64) {
        int cnt = min(64, s1 - base);
        int sv = (base + lane < s1) ? csr[base + lane] : 0;
        for (int t = 0; t < cnt; ++t) {
            int sidx = __shfl(sv, t);
            if (lane < NOUT) acc += zl[(long)sidx * NOUT + lane];
        }
    }
    if (lane >= NOUT) return;
    float deg = (float)(s1 - s0);
    float r = acc / fmaxf(deg, 1.f) + zr[(long)wid * NOUT + lane];
    if (MODE == 1 || MODE == 2) {
        float sc = g[lane] * rsqrtf(v[lane] + 1e-5f);
        r = (r - m[lane]) * sc + bb[lane];
    }
    if (MODE == 0 || MODE == 1) r = fmaxf(r, 0.f);
    out[(long)wid * NOUT + lane] = r;
}

// ---------------- host ----------------
extern "C" void kernel_launch(void* const* d_in, const int* in_sizes, int n_in,
                              void* d_out, int out_size, void* d_ws, size_t ws_size,
                              hipStream_t stream) {
    const float* x    = (const float*)d_in[0];
    const int*   ei   = (const int*)d_in[1];
    const float* w1l  = (const float*)d_in[2];
    const float* w1r  = (const float*)d_in[3];
    const float* b1   = (const float*)d_in[4];
    const float* wxl  = (const float*)d_in[5];
    const float* wxr  = (const float*)d_in[6];
    const float* bx   = (const float*)d_in[7];
    const float* w2l  = (const float*)d_in[8];
    const float* w2r  = (const float*)d_in[9];
    const float* b2   = (const float*)d_in[10];
    const float* bn3g = (const float*)d_in[11];
    const float* bn3b = (const float*)d_in[12];
    const float* bn3m = (const float*)d_in[13];
    const float* bn3v = (const float*)d_in[14];
    const float* bn2g = (const float*)d_in[15];
    const float* bn2b = (const float*)d_in[16];
    const float* bn2m = (const float*)d_in[17];
    const float* bn2v = (const float*)d_in[18];
    float* out = (float*)d_out;

    char* p = (char*)d_ws;
    auto alloc = [&](size_t bytes) -> void* {
        void* r = (void*)p;
        p += (bytes + 255) & ~(size_t)255;
        return r;
    };
    int*   flag   = (int*)alloc(4);
    int*   cursor = (int*)alloc((size_t)NNODES * 4);        // deg, then scatter cursors
    int*   offs   = (int*)alloc((size_t)(NNODES + 1) * 4);
    int*   bsums  = (int*)alloc(128 * 4);
    int*   csr    = (int*)alloc((size_t)NEDGES * 4);
    float* bufA   = (float*)alloc((size_t)NNODES * 64 * 4); // h (reused between layers)
    float* bufC   = (float*)alloc((size_t)NNODES * 64 * 4); // zl
    float* bufD   = (float*)alloc((size_t)NNODES * 64 * 4); // zr

    hipMemsetAsync(cursor, 0, (size_t)NNODES * 4, stream);
    detect_kernel<<<1, 64, 0, stream>>>(ei, flag);
    hist_kernel<<<6250, 256, 0, stream>>>(ei, flag, cursor);
    scan_bsum<<<98, 256, 0, stream>>>(cursor, bsums);
    scan_partials<<<1, 128, 0, stream>>>(bsums, 98);
    scan_write<<<98, 256, 0, stream>>>(cursor, bsums, offs);
    copy_kernel<<<391, 256, 0, stream>>>(offs, cursor);
    scatter_kernel<<<6250, 256, 0, stream>>>(ei, flag, cursor, csr);

    // layer 1: x[N,128] -> h1[N,64] (relu)
    gemm_fused<128, 64><<<1024, 256, 0, stream>>>(x, w1l, w1r, b1, bufC, bufD, NNODES);
    combine_kernel<64, 0><<<25000, 256, 0, stream>>>(bufC, bufD, offs, csr,
                                                     nullptr, nullptr, nullptr, nullptr, bufA);
    // layer 2: h1 -> h2[N,64] (bn3 + relu)
    gemm_fused<64, 64><<<1024, 256, 0, stream>>>(bufA, wxl, wxr, bx, bufC, bufD, NNODES);
    combine_kernel<64, 1><<<25000, 256, 0, stream>>>(bufC, bufD, offs, csr,
                                                     bn3g, bn3b, bn3m, bn3v, bufA);
    // layer 3: h2 -> out[N,40] (bn2)
    gemm_fused<64, 40><<<1024, 256, 0, stream>>>(bufA, w2l, w2r, b2, bufC, bufD, NNODES);
    combine_kernel<40, 2><<<25000, 256, 0, stream>>>(bufC, bufD, offs, csr,
                                                     bn2g, bn2b, bn2m, bn2v, out);
}